// Round 2
// baseline (888.447 us; speedup 1.0000x reference)
//
#include <hip/hip_runtime.h>

// Equivariant linear: irreps [(32,1),(16,3),(8,5),(4,7)], DIM=148.
// out[n, off_b + v*d + i] = mul^-0.5 * sum_u x[n, off_b + u*d + i] * w_b[u*mul + v]
//
// v3 theory: v2 (LDS store-staging, 13.3 KB/WG) was latency-bound at
// 12 waves/CU (Occupancy 29%, VALUBusy 10%, HBM 34%). The LDS buffer bought
// nothing: WRITE_SIZE showed +23% over-write anyway (segment-boundary lines
// split across flush phases, evicted between them), plus 8 barriers and 1.4M
// bank-conflict cycles per dispatch. This version:
//  - NO LDS, no barriers. Lane = row; reads AND writes are per-lane
//    contiguous 16B chunks (consecutive instrs touch consecutive chunks of
//    the same 64B line -> L1 read reuse / L2 store merge within a few cycles).
//  - VGPR-capped at 85 via __launch_bounds__(128, 6) -> 6 waves/SIMD =
//    24 waves/CU (2x the in-flight memory of v2).
//  - 128-thread WGs (2 independent waves) to stay under the WGs/CU HW cap.

#define ROWF 148   // floats per row

template <int MUL, int D, int OFF>
__device__ __forceinline__ void proc_store(const float* __restrict__ xr,
                                           float* __restrict__ orow,
                                           const float* __restrict__ w,
                                           float scale) {
    constexpr int SZ  = MUL * D;
    constexpr int NF4 = SZ / 4;

    // Load this block's x segment: NF4 consecutive f4 loads (16B steps) ->
    // full 64B-line utilization via L1 within a ~4-instr window.
    const float4* p = (const float4*)(xr + OFF);  // OFF%4==0, x 16B-aligned
    float xv[SZ];
#pragma unroll
    for (int j = 0; j < NF4; ++j) {
        float4 v = p[j];
        xv[4 * j + 0] = v.x;
        xv[4 * j + 1] = v.y;
        xv[4 * j + 2] = v.z;
        xv[4 * j + 3] = v.w;
    }

    float acc[SZ];
#pragma unroll
    for (int k = 0; k < SZ; ++k) acc[k] = 0.0f;

#pragma unroll
    for (int u = 0; u < MUL; ++u) {
#pragma unroll
        for (int v = 0; v < MUL; ++v) {
            // w is a uniform kernel-arg pointer, constexpr index -> s_load,
            // cached in K$ after the first WG per CU.
            float wv = w[u * MUL + v];
#pragma unroll
            for (int i = 0; i < D; ++i) {
                acc[v * D + i] += xv[u * D + i] * wv;
            }
        }
    }

    // Direct stores: consecutive instrs write consecutive 16B of this lane's
    // row segment -> store queue / L2 merges into full lines. Fire-and-forget
    // (no waits); overlaps with next block's loads/FMAs.
    float4* o4 = (float4*)(orow + OFF);
#pragma unroll
    for (int j = 0; j < NF4; ++j) {
        float4 o;
        o.x = acc[4 * j + 0] * scale;
        o.y = acc[4 * j + 1] * scale;
        o.z = acc[4 * j + 2] * scale;
        o.w = acc[4 * j + 3] * scale;
        o4[j] = o;
    }
}

__global__ __launch_bounds__(128, 6) void eqlin_kernel(
    const float* __restrict__ x,
    const float* __restrict__ w0,
    const float* __restrict__ w1,
    const float* __restrict__ w2,
    const float* __restrict__ w3,
    float* __restrict__ out) {
    const size_t row = (size_t)blockIdx.x * 128 + threadIdx.x;
    const float* xr = x + row * ROWF;
    float* orow = out + row * ROWF;

    proc_store<32, 1, 0>(xr, orow, w0, 0.17677669529663687f);   // 32^-0.5
    proc_store<16, 3, 32>(xr, orow, w1, 0.25f);                 // 16^-0.5
    proc_store<8, 5, 80>(xr, orow, w2, 0.35355339059327373f);   //  8^-0.5
    proc_store<4, 7, 120>(xr, orow, w3, 0.5f);                  //  4^-0.5
}

extern "C" void kernel_launch(void* const* d_in, const int* in_sizes, int n_in,
                              void* d_out, int out_size, void* d_ws, size_t ws_size,
                              hipStream_t stream) {
    const float* x  = (const float*)d_in[0];
    const float* w0 = (const float*)d_in[1];
    const float* w1 = (const float*)d_in[2];
    const float* w2 = (const float*)d_in[3];
    const float* w3 = (const float*)d_in[4];
    float* out = (float*)d_out;

    const int N = in_sizes[0] / ROWF;  // 524288
    const int wgs = N / 128;           // 4096 (exact)

    eqlin_kernel<<<dim3(wgs), dim3(128), 0, stream>>>(x, w0, w1, w2, w3, out);
}

// Round 3
// 535.684 us; speedup vs baseline: 1.6585x; 1.6585x over previous
//
#include <hip/hip_runtime.h>

// Equivariant linear: irreps [(32,1),(16,3),(8,5),(4,7)], DIM=148.
// out[n, off_b + v*d + i] = mul^-0.5 * sum_u x[n, off_b + u*d + i] * w_b[u*mul + v]
//
// v4. Measured facts driving this design:
//  - R2: store coalescing is PER-INSTRUCTION across lanes; L2 does NOT merge
//    separate 16B stores (WRITE_SIZE 3.1x ideal). Stores must be wide
//    lane-coalesced full lines -> LDS-staged flush.
//  - R2: per-lane strided reads thrash L1 above ~12-16 waves/CU (FETCH 2x at
//    18-24 waves); at 12 waves (R1) FETCH was 1.004x ideal. Cap ~8 waves/CU.
//  - R1: flushing per-block wrote boundary lines twice (+23%); flush must
//    cover whole rows in one phase. 32 rows x 592 B = 18944 B = exactly 296
//    aligned 64B lines.
//  - R1: 4 __syncthreads per tile each drain vmcnt(0) -> serialize. v4 has ONE.
//
// Structure: 1-wave WG, 32-row tile. lane = (row = lane&31, half = lane>>5).
// half 0: blocks {32x0e, 4x3o} (1136 FMA); half 1: blocks {16x1o, 8x2e}
// (1088 FMA). Divergent branches keep weight indices constexpr -> s_load.
// Results go to a full-row LDS image; single sync; single coalesced flush.
// LDS 18944 B -> 8 WGs/CU (2 waves/SIMD), in-flight ~19KB/wave >> BW-saturation
// requirement.

#define ROWF  148                     // floats per row
#define TROWS 32                      // rows per workgroup
#define TILE_F4 (TROWS * ROWF / 4)    // 1184 float4 per tile (= 18*64 + 32)

__device__ __forceinline__ float xc(const float4* v, int k) {
    // constexpr-indexed component access; stays in registers after unroll
    return ((const float*)v)[k];
}

template <int NF4>
__device__ __forceinline__ void loadf4(const float* __restrict__ p,
                                       float4* __restrict__ dst) {
#pragma unroll
    for (int j = 0; j < NF4; ++j) dst[j] = ((const float4*)p)[j];
}

// Compute one irrep block for this lane's row; write scaled result to the
// row's LDS image (16B-aligned: ROWF%4==0, OFF%4==0).
template <int MUL, int D>
__device__ __forceinline__ void comp_blk(const float4* __restrict__ xin,
                                         const float* __restrict__ w,
                                         float scale,
                                         float* __restrict__ ldsout) {
    constexpr int SZ  = MUL * D;
    constexpr int NF4 = SZ / 4;

    float acc[SZ];
#pragma unroll
    for (int k = 0; k < SZ; ++k) acc[k] = 0.0f;

#pragma unroll
    for (int u = 0; u < MUL; ++u) {
#pragma unroll
        for (int v = 0; v < MUL; ++v) {
            // constexpr index on uniform kernel-arg pointer -> s_load (K$-hot)
            float wv = w[u * MUL + v];
#pragma unroll
            for (int i = 0; i < D; ++i) {
                acc[v * D + i] += xc(xin, u * D + i) * wv;
            }
        }
    }

    float4* o4 = (float4*)ldsout;
#pragma unroll
    for (int j = 0; j < NF4; ++j) {
        float4 o;
        o.x = acc[4 * j + 0] * scale;
        o.y = acc[4 * j + 1] * scale;
        o.z = acc[4 * j + 2] * scale;
        o.w = acc[4 * j + 3] * scale;
        o4[j] = o;  // ds_write_b128; 4-way bank alias max (row stride 148 words)
    }
}

__global__ __launch_bounds__(64) void eqlin_kernel(
    const float* __restrict__ x,
    const float* __restrict__ w0,
    const float* __restrict__ w1,
    const float* __restrict__ w2,
    const float* __restrict__ w3,
    float* __restrict__ out) {
    __shared__ float lds[TROWS * ROWF];  // 18944 B -> 8 WGs/CU

    const int lane = threadIdx.x;        // one wave per WG
    const int r    = lane & 31;          // row within tile
    const int h    = lane >> 5;          // which block-pair this lane computes
    const size_t grow = (size_t)blockIdx.x * TROWS + r;
    const float* xr = x + grow * ROWF;
    float* lrow = lds + r * ROWF;

    if (h == 0) {
        // blocks 0 (32x0e, cols [0,32)) and 3 (4x3o, cols [120,148)) : 1136 FMA
        float4 xb0[8], xb3[7];
        loadf4<8>(xr + 0, xb0);      // issue both segments' loads up front;
        loadf4<7>(xr + 120, xb3);    // latency hides under co-resident waves
        comp_blk<32, 1>(xb0, w0, 0.17677669529663687f, lrow + 0);    // 32^-0.5
        comp_blk<4, 7>(xb3, w3, 0.5f, lrow + 120);                   //  4^-0.5
    } else {
        // blocks 1 (16x1o, cols [32,80)) and 2 (8x2e, cols [80,120)) : 1088 FMA
        float4 xb1[12], xb2[10];
        loadf4<12>(xr + 32, xb1);
        loadf4<10>(xr + 80, xb2);
        comp_blk<16, 3>(xb1, w1, 0.25f, lrow + 32);                  // 16^-0.5
        comp_blk<8, 5>(xb2, w2, 0.35355339059327373f, lrow + 80);    //  8^-0.5
    }

    __syncthreads();  // single sync per tile (1-wave WG: waitcnt + cheap barrier)

    // Single coalesced flush: whole tile, consecutive lanes -> consecutive 16B,
    // tile base = bid*18944 B (64B-aligned), covers exactly 296 full lines once.
    const float4* l4 = (const float4*)lds;
    float4* dst = (float4*)out + (size_t)blockIdx.x * TILE_F4;
#pragma unroll
    for (int k = 0; k < 18; ++k) {
        dst[k * 64 + lane] = l4[k * 64 + lane];
    }
    if (lane < 32) {  // 1184 = 18*64 + 32 tail
        dst[18 * 64 + lane] = l4[18 * 64 + lane];
    }
}

extern "C" void kernel_launch(void* const* d_in, const int* in_sizes, int n_in,
                              void* d_out, int out_size, void* d_ws, size_t ws_size,
                              hipStream_t stream) {
    const float* x  = (const float*)d_in[0];
    const float* w0 = (const float*)d_in[1];
    const float* w1 = (const float*)d_in[2];
    const float* w2 = (const float*)d_in[3];
    const float* w3 = (const float*)d_in[4];
    float* out = (float*)d_out;

    const int N = in_sizes[0] / ROWF;  // 524288
    const int wgs = N / TROWS;         // 16384 (exact)

    eqlin_kernel<<<dim3(wgs), dim3(64), 0, stream>>>(x, w0, w1, w2, w3, out);
}